// Round 3
// baseline (105.751 us; speedup 1.0000x reference)
//
#include <hip/hip_runtime.h>
#include <hip/hip_bf16.h>
#include <math.h>

#define BB 32
#define NP 576
#define WW 32
#define DD 256
// GEMM view: M = 32*576 = 18432, N = 32*32 = 1024, K = 256.
// M-tiles: 5 per image (4 full 128s + one 64-valid), N-tiles: 8 x 128.

typedef __bf16 bf16x8 __attribute__((ext_vector_type(8)));
typedef float f32x4 __attribute__((ext_vector_type(4)));

__device__ __forceinline__ unsigned short f2bf(float f) {
  unsigned int u = __float_as_uint(f);
  u += 0x7FFFu + ((u >> 16) & 1u);
  return (unsigned short)(u >> 16);
}

// Async global->LDS DMA, 16 B per lane. gptr is PER-LANE (arbitrary addresses,
// 16B-aligned); LDS destination is wave-uniform base + lane*16 (m104 semantics).
__device__ __forceinline__ void gld_lds16(const unsigned short* g, unsigned short* l) {
  __builtin_amdgcn_global_load_lds(
      (const __attribute__((address_space(1))) void*)g,
      (__attribute__((address_space(3))) void*)l, 16, 0, 0);
}

// Kernel A: fused L2-normalize + bf16 cast. One wave per row of 256 floats.
__global__ __launch_bounds__(256) void norm_cast_kernel(
    const float* __restrict__ img, const float* __restrict__ con,
    unsigned short* __restrict__ img_bf, unsigned short* __restrict__ con_bf) {
  int row = blockIdx.x * 4 + (threadIdx.x >> 6);
  int lane = threadIdx.x & 63;
  const int n_img = BB * NP;  // 18432 rows
  const float* src;
  unsigned short* dst;
  if (row < n_img) {
    src = img + (size_t)row * DD;
    dst = img_bf + (size_t)row * DD;
  } else {
    int r2 = row - n_img;
    src = con + (size_t)r2 * DD;
    dst = con_bf + (size_t)r2 * DD;
  }
  float4 v = ((const float4*)src)[lane];
  float ss = v.x * v.x + v.y * v.y + v.z * v.z + v.w * v.w;
  #pragma unroll
  for (int off = 1; off < 64; off <<= 1) ss += __shfl_xor(ss, off);
  float inv = 1.0f / fmaxf(sqrtf(ss), 1e-12f);
  ushort4 o;
  o.x = f2bf(v.x * inv);
  o.y = f2bf(v.y * inv);
  o.z = f2bf(v.z * inv);
  o.w = f2bf(v.w * inv);
  ((ushort4*)dst)[lane] = o;
}

// Kernel B: 128x128-tile GEMM (K=256, BK=64) with fused max-over-rows epilogue.
// Staging via global_load_lds: per chunk, each wave issues 4 A-seg + 4 B-seg
// DMAs. Seg s (0..15) = (gi = s>>1 row-group of 16, kk = s&1 K-half of 32).
// Lane l = q*16+r fetches row gi*16+r, elements [kb*64 + kk*32 + q*8, +8) ->
// LDS seg lands in exact MFMA A/B fragment order (lane-linear, conflict-free).
// Fragment layouts (verified rounds 1-2):
//   A-frag: lane(q,r) holds A[row=r][k=q*8+j] (16B contiguous)
//   D-frag: lane holds D[row=q*4+reg][col=r]
__global__ __launch_bounds__(256, 3) void gemm_max_kernel(
    const unsigned short* __restrict__ img_bf,  // 18432 x 256
    const unsigned short* __restrict__ con_bf,  // 1024 x 256
    float* __restrict__ P) {                    // [160][1024] partial maxes
  int bx = blockIdx.x;
  int bw = bx & 7;    // N-tile 0..7
  int bm = bx >> 3;   // M-tile 0..159
  int m = bm / 5;
  int t = bm - m * 5;
  int p0 = m * NP + t * 128;  // global row base (t==4: rows 64..127 invalid)
  int w0 = bw * 128;

  __shared__ __align__(16) unsigned short ldsA[8192];  // 16 segs x 512 elems = 16 KB
  __shared__ __align__(16) unsigned short ldsB[8192];
  __shared__ float sm[256];

  int tid = threadIdx.x;
  int wid = tid >> 6;
  int lane = tid & 63;
  int q = lane >> 4;   // 0..3
  int r = lane & 15;   // 0..15
  int wp = wid >> 1;   // row-half 0..1 (64 rows each)
  int wc = wid & 1;    // col-half 0..1 (64 cols each)

  f32x4 acc[4][4];
  #pragma unroll
  for (int i = 0; i < 4; ++i)
    #pragma unroll
    for (int j = 0; j < 4; ++j) acc[i][j] = (f32x4){0.f, 0.f, 0.f, 0.f};

  // Per-lane invariant part of the staging addresses.
  const unsigned short* gA0 = img_bf + (size_t)p0 * DD;
  const unsigned short* gB0 = con_bf + (size_t)w0 * DD;

  for (int kb = 0; kb < 4; ++kb) {
    __syncthreads();  // previous chunk's LDS fully consumed before DMA overwrite
    #pragma unroll
    for (int u = 0; u < 4; ++u) {
      int s = wid * 4 + u;      // seg 0..15 (uniform per wave)
      int gi = s >> 1;
      int kk2 = s & 1;
      size_t goff = (size_t)(gi * 16 + r) * DD + kb * 64 + kk2 * 32 + q * 8;
      gld_lds16(gA0 + goff, &ldsA[s * 512]);
      gld_lds16(gB0 + goff, &ldsB[s * 512]);
    }
    __syncthreads();  // drains vmcnt (DMA complete) + all waves staged
    #pragma unroll
    for (int kk = 0; kk < 2; ++kk) {
      bf16x8 af[4], bfr[4];
      #pragma unroll
      for (int pi = 0; pi < 4; ++pi)
        af[pi] = *(const bf16x8*)&ldsA[(((wp * 4 + pi) << 1) | kk) * 512 + lane * 8];
      #pragma unroll
      for (int wj = 0; wj < 4; ++wj)
        bfr[wj] = *(const bf16x8*)&ldsB[(((wc * 4 + wj) << 1) | kk) * 512 + lane * 8];
      #pragma unroll
      for (int pi = 0; pi < 4; ++pi)
        #pragma unroll
        for (int wj = 0; wj < 4; ++wj)
          acc[pi][wj] =
              __builtin_amdgcn_mfma_f32_16x16x32_bf16(af[pi], bfr[wj], acc[pi][wj], 0, 0, 0);
    }
  }

  // Epilogue: max over this wave's 64 rows for each of its 64 cols.
  float mxw[4];
  #pragma unroll
  for (int wj = 0; wj < 4; ++wj) {
    float v = -1e30f;
    #pragma unroll
    for (int pi = 0; pi < 4; ++pi) {
      v = fmaxf(v, fmaxf(fmaxf(acc[pi][wj][0], acc[pi][wj][1]),
                         fmaxf(acc[pi][wj][2], acc[pi][wj][3])));
    }
    v = fmaxf(v, __shfl_xor(v, 16));
    v = fmaxf(v, __shfl_xor(v, 32));
    mxw[wj] = v;
  }
  __syncthreads();
  if (lane < 16) {
    #pragma unroll
    for (int wj = 0; wj < 4; ++wj)
      sm[wp * 128 + wc * 64 + wj * 16 + lane] = mxw[wj];
  }
  __syncthreads();
  if (tid < 128) {
    float v = sm[tid];                        // rows 0..63 (always valid)
    if (t != 4) v = fmaxf(v, sm[128 + tid]);  // rows 64..127 only if valid
    P[(size_t)bm * 1024 + w0 + tid] = v;
  }
}

// Kernel C: reduce partial maxes over the 5 M-tiles of each image, then
// masked mean over valid concepts -> sims[m*32+c].
__global__ __launch_bounds__(256) void reduce_kernel(
    const float* __restrict__ P, const int* __restrict__ lengths,
    float* __restrict__ sims) {
  int pair = blockIdx.x * 4 + (threadIdx.x >> 6);  // 0..1023
  int lane = threadIdx.x & 63;
  int m = pair >> 5;
  int c = pair & 31;
  int w = lane & 31;
  const float* base = P + (size_t)(m * 5) * 1024 + c * 32 + w;
  float v = base[0];
  v = fmaxf(v, base[1024]);
  v = fmaxf(v, base[2048]);
  v = fmaxf(v, base[3072]);
  v = fmaxf(v, base[4096]);
  int len = lengths[c];
  float contrib = (w < len) ? v : 0.0f;
  #pragma unroll
  for (int off = 1; off < 32; off <<= 1) contrib += __shfl_xor(contrib, off);
  if (lane == 0) sims[pair] = contrib / (float)len;
}

// Kernel D: fold 1024 sims into the SigLIP-style loss.
__global__ __launch_bounds__(256) void loss_kernel(
    const float* __restrict__ sims, const float* __restrict__ lscale,
    const float* __restrict__ lbias, float* __restrict__ out) {
  float tt = expf(fminf(fmaxf(lscale[0], -10.0f), 10.0f));
  float bias = lbias[0];
  int tid = threadIdx.x;
  float acc = 0.0f;
  for (int p = tid; p < BB * BB; p += 256) {
    int mm = p >> 5;
    int cc = p & 31;
    float lg = fminf(fmaxf(tt * sims[p] + bias, -50.0f), 50.0f);
    float x = (mm == cc) ? lg : -lg;
    float ls = (x >= 0.0f) ? -log1pf(expf(-x)) : (x - log1pf(expf(x)));
    acc += ls;
  }
  #pragma unroll
  for (int off = 1; off < 64; off <<= 1) acc += __shfl_xor(acc, off);
  __shared__ float s[4];
  if ((tid & 63) == 0) s[tid >> 6] = acc;
  __syncthreads();
  if (tid == 0) out[0] = -(s[0] + s[1] + s[2] + s[3]) / (float)(BB * BB);
}

extern "C" void kernel_launch(void* const* d_in, const int* in_sizes, int n_in,
                              void* d_out, int out_size, void* d_ws, size_t ws_size,
                              hipStream_t stream) {
  const float* img = (const float*)d_in[0];  // (32, 576, 256) f32
  const float* con = (const float*)d_in[1];  // (32, 32, 256) f32
  const int* lens = (const int*)d_in[2];     // (32,) i32
  const float* lsc = (const float*)d_in[3];  // (1,)
  const float* lbi = (const float*)d_in[4];  // (1,)

  unsigned short* img_bf = (unsigned short*)d_ws;              // 18432*256 bf16
  unsigned short* con_bf = img_bf + (size_t)BB * NP * DD;      // 1024*256 bf16
  float* P = (float*)(con_bf + (size_t)BB * WW * DD);          // 160*1024 f32
  float* sims = P + (size_t)160 * 1024;                        // 1024 f32

  norm_cast_kernel<<<(BB * NP + BB * WW) / 4, 256, 0, stream>>>(img, con, img_bf, con_bf);
  gemm_max_kernel<<<160 * 8, 256, 0, stream>>>(img_bf, con_bf, P);
  reduce_kernel<<<256, 256, 0, stream>>>(P, lens, sims);
  loss_kernel<<<1, 256, 0, stream>>>(sims, lsc, lbi, (float*)d_out);
}

// Round 4
// 99.056 us; speedup vs baseline: 1.0676x; 1.0676x over previous
//
#include <hip/hip_runtime.h>
#include <hip/hip_bf16.h>
#include <math.h>

#define BB 32
#define NP 576
#define WW 32
#define DD 256
// GEMM view: M = 18432, N = 1024, K = 256. M-tiles: 5 per image (last is
// 64-valid), N-tiles: 8 x 128.
//
// Intermediate layout (MFMA-ready, written by norm_cast_kernel):
// for each 16-row group g: 8 segs of 512 bf16 (1 KiB), seg s = kb*2+kk
// (kb = K-chunk of 64, kk = K-half of 32). Within a seg, index
// (q*16+r)*8 + j  <->  element (row g*16+r, k = kb*64 + kk*32 + q*8 + j).
// This is exactly the 16x16x32 A/B fragment image for lane l = q*16+r, so
// global_load_lds with lane-contiguous addresses (lane l reads base + l*16B)
// is BOTH fully coalesced AND lands in LDS in frag order.

typedef __bf16 bf16x8 __attribute__((ext_vector_type(8)));
typedef float f32x4 __attribute__((ext_vector_type(4)));

__device__ __forceinline__ unsigned short f2bf(float f) {
  unsigned int u = __float_as_uint(f);
  u += 0x7FFFu + ((u >> 16) & 1u);
  return (unsigned short)(u >> 16);
}

// Async global->LDS DMA, 16 B per lane; lane l's global addr must be the
// data destined for LDS base + l*16 (HW writes lane-linear).
__device__ __forceinline__ void gld_lds16(const unsigned short* g, unsigned short* l) {
  __builtin_amdgcn_global_load_lds(
      (const __attribute__((address_space(1))) void*)g,
      (__attribute__((address_space(3))) void*)l, 16, 0, 0);
}

// Kernel A: fused L2-normalize + bf16 cast + tiled-layout shuffle.
// One wave per row of 256 floats; lane L holds elements k = 4L..4L+3.
// Target: seg s = L>>3, q = (L>>1)&3, j0 = (L&1)*4 -> one ushort4 store.
__global__ __launch_bounds__(256) void norm_cast_kernel(
    const float* __restrict__ img, const float* __restrict__ con,
    unsigned short* __restrict__ img_t, unsigned short* __restrict__ con_t) {
  int row = blockIdx.x * 4 + (threadIdx.x >> 6);
  int lane = threadIdx.x & 63;
  const int n_img = BB * NP;  // 18432
  const float* src;
  unsigned short* dstbase;
  int prow;
  if (row < n_img) {
    src = img + (size_t)row * DD;
    dstbase = img_t;
    prow = row;
  } else {
    prow = row - n_img;
    src = con + (size_t)prow * DD;
    dstbase = con_t;
  }
  float4 v = ((const float4*)src)[lane];
  float ss = v.x * v.x + v.y * v.y + v.z * v.z + v.w * v.w;
  #pragma unroll
  for (int off = 1; off < 64; off <<= 1) ss += __shfl_xor(ss, off);
  float inv = 1.0f / fmaxf(sqrtf(ss), 1e-12f);
  ushort4 o;
  o.x = f2bf(v.x * inv);
  o.y = f2bf(v.y * inv);
  o.z = f2bf(v.z * inv);
  o.w = f2bf(v.w * inv);
  size_t di = ((size_t)(prow >> 4) * 8 + (lane >> 3)) * 512 +
              (size_t)((((lane >> 1) & 3) * 16 + (prow & 15)) * 8) + (lane & 1) * 4;
  *(ushort4*)(dstbase + di) = o;
}

// Kernel B: 128x128-tile GEMM (K=256, BK=64) with fused max-over-rows epilogue.
// Staging: per chunk each wave issues 4 A-seg + 4 B-seg DMAs; seg s = gi*2+kk2
// (gi = 16-row group 0..7, kk2 = K-half). Global source is one contiguous
// 1-KiB block of the tiled layout. Frag layouts (verified rounds 1-3):
//   A-frag: lane(q,r) holds A[row=r][k=q*8+j];  D: row=q*4+reg, col=r.
__global__ __launch_bounds__(256, 3) void gemm_max_kernel(
    const unsigned short* __restrict__ img_t,  // tiled 18432 x 256
    const unsigned short* __restrict__ con_t,  // tiled 1024 x 256
    float* __restrict__ P) {                   // [160][1024] partial maxes
  int bx = blockIdx.x;
  int bw = bx & 7;    // N-tile 0..7
  int bm = bx >> 3;   // M-tile 0..159
  int m = bm / 5;
  int t = bm - m * 5;
  int p0 = m * NP + t * 128;  // 16-aligned; t==4: rows 64..127 invalid
  int w0 = bw * 128;

  __shared__ __align__(16) unsigned short ldsA[8192];  // 16 segs x 512
  __shared__ __align__(16) unsigned short ldsB[8192];
  __shared__ float sm[256];

  int tid = threadIdx.x;
  int wid = tid >> 6;
  int lane = tid & 63;
  int wp = wid >> 1;  // row-half
  int wc = wid & 1;   // col-half

  f32x4 acc[4][4];
  #pragma unroll
  for (int i = 0; i < 4; ++i)
    #pragma unroll
    for (int j = 0; j < 4; ++j) acc[i][j] = (f32x4){0.f, 0.f, 0.f, 0.f};

  const unsigned short* gA = img_t + (size_t)(p0 >> 4) * 4096 + lane * 8;
  const unsigned short* gB = con_t + (size_t)(w0 >> 4) * 4096 + lane * 8;

  for (int kb = 0; kb < 4; ++kb) {
    __syncthreads();  // previous chunk's LDS fully consumed
    #pragma unroll
    for (int u = 0; u < 4; ++u) {
      int s = wid * 4 + u;  // seg 0..15 (wave-uniform)
      int gi = s >> 1;
      int kk2 = s & 1;
      size_t goff = ((size_t)gi * 8 + kb * 2 + kk2) * 512;
      gld_lds16(gA + goff, &ldsA[s * 512]);
      gld_lds16(gB + goff, &ldsB[s * 512]);
    }
    __syncthreads();  // drains vmcnt (DMA complete) for all waves
    #pragma unroll
    for (int kk = 0; kk < 2; ++kk) {
      bf16x8 af[4], bfr[4];
      #pragma unroll
      for (int pi = 0; pi < 4; ++pi)
        af[pi] = *(const bf16x8*)&ldsA[(((wp * 4 + pi) << 1) | kk) * 512 + lane * 8];
      #pragma unroll
      for (int wj = 0; wj < 4; ++wj)
        bfr[wj] = *(const bf16x8*)&ldsB[(((wc * 4 + wj) << 1) | kk) * 512 + lane * 8];
      #pragma unroll
      for (int pi = 0; pi < 4; ++pi)
        #pragma unroll
        for (int wj = 0; wj < 4; ++wj)
          acc[pi][wj] =
              __builtin_amdgcn_mfma_f32_16x16x32_bf16(af[pi], bfr[wj], acc[pi][wj], 0, 0, 0);
    }
  }

  // Epilogue: max over this wave's 64 rows for each of its 64 cols.
  float mxw[4];
  #pragma unroll
  for (int wj = 0; wj < 4; ++wj) {
    float v = -1e30f;
    #pragma unroll
    for (int pi = 0; pi < 4; ++pi) {
      v = fmaxf(v, fmaxf(fmaxf(acc[pi][wj][0], acc[pi][wj][1]),
                         fmaxf(acc[pi][wj][2], acc[pi][wj][3])));
    }
    v = fmaxf(v, __shfl_xor(v, 16));
    v = fmaxf(v, __shfl_xor(v, 32));
    mxw[wj] = v;
  }
  __syncthreads();
  if (lane < 16) {
    #pragma unroll
    for (int wj = 0; wj < 4; ++wj)
      sm[wp * 128 + wc * 64 + wj * 16 + lane] = mxw[wj];
  }
  __syncthreads();
  if (tid < 128) {
    float v = sm[tid];                        // rows 0..63 always valid
    if (t != 4) v = fmaxf(v, sm[128 + tid]);  // rows 64..127 only if valid
    P[(size_t)bm * 1024 + w0 + tid] = v;
  }
}

// Kernel C: reduce partial maxes over the 5 M-tiles, masked mean -> sims.
__global__ __launch_bounds__(256) void reduce_kernel(
    const float* __restrict__ P, const int* __restrict__ lengths,
    float* __restrict__ sims) {
  int pair = blockIdx.x * 4 + (threadIdx.x >> 6);  // 0..1023
  int lane = threadIdx.x & 63;
  int m = pair >> 5;
  int c = pair & 31;
  int w = lane & 31;
  const float* base = P + (size_t)(m * 5) * 1024 + c * 32 + w;
  float v = base[0];
  v = fmaxf(v, base[1024]);
  v = fmaxf(v, base[2048]);
  v = fmaxf(v, base[3072]);
  v = fmaxf(v, base[4096]);
  int len = lengths[c];
  float contrib = (w < len) ? v : 0.0f;
  #pragma unroll
  for (int off = 1; off < 32; off <<= 1) contrib += __shfl_xor(contrib, off);
  if (lane == 0) sims[pair] = contrib / (float)len;
}

// Kernel D: fold 1024 sims into the SigLIP-style loss.
__global__ __launch_bounds__(256) void loss_kernel(
    const float* __restrict__ sims, const float* __restrict__ lscale,
    const float* __restrict__ lbias, float* __restrict__ out) {
  float tt = expf(fminf(fmaxf(lscale[0], -10.0f), 10.0f));
  float bias = lbias[0];
  int tid = threadIdx.x;
  float acc = 0.0f;
  for (int p = tid; p < BB * BB; p += 256) {
    int mm = p >> 5;
    int cc = p & 31;
    float lg = fminf(fmaxf(tt * sims[p] + bias, -50.0f), 50.0f);
    float x = (mm == cc) ? lg : -lg;
    float ls = (x >= 0.0f) ? -log1pf(expf(-x)) : (x - log1pf(expf(x)));
    acc += ls;
  }
  #pragma unroll
  for (int off = 1; off < 64; off <<= 1) acc += __shfl_xor(acc, off);
  __shared__ float s[4];
  if ((tid & 63) == 0) s[tid >> 6] = acc;
  __syncthreads();
  if (tid == 0) out[0] = -(s[0] + s[1] + s[2] + s[3]) / (float)(BB * BB);
}

extern "C" void kernel_launch(void* const* d_in, const int* in_sizes, int n_in,
                              void* d_out, int out_size, void* d_ws, size_t ws_size,
                              hipStream_t stream) {
  const float* img = (const float*)d_in[0];  // (32, 576, 256) f32
  const float* con = (const float*)d_in[1];  // (32, 32, 256) f32
  const int* lens = (const int*)d_in[2];     // (32,) i32
  const float* lsc = (const float*)d_in[3];  // (1,)
  const float* lbi = (const float*)d_in[4];  // (1,)

  unsigned short* img_t = (unsigned short*)d_ws;           // 18432*256 bf16, tiled
  unsigned short* con_t = img_t + (size_t)BB * NP * DD;    // 1024*256 bf16, tiled
  float* P = (float*)(con_t + (size_t)BB * WW * DD);       // 160*1024 f32
  float* sims = P + (size_t)160 * 1024;                    // 1024 f32

  norm_cast_kernel<<<(BB * NP + BB * WW) / 4, 256, 0, stream>>>(img, con, img_t, con_t);
  gemm_max_kernel<<<160 * 8, 256, 0, stream>>>(img_t, con_t, P);
  reduce_kernel<<<256, 256, 0, stream>>>(P, lens, sims);
  loss_kernel<<<1, 256, 0, stream>>>(sims, lsc, lbi, (float*)d_out);
}